// Round 3
// baseline (229.450 us; speedup 1.0000x reference)
//
#include <hip/hip_runtime.h>

#define KFEAT 32
#define NB 4   // batch elements per block (2 pairs)

__device__ __forceinline__ float clip01(float v) {
    return fminf(fmaxf(v, 0.0f), 1.0f);
}

// ---------------- fp32 table -> bf16 (RTNE) conversion, runs every launch ----------------
__global__ __launch_bounds__(256) void convert_table_bf16(
    const float* __restrict__ src, ushort* __restrict__ dst, int n4)
{
    int i = blockIdx.x * blockDim.x + threadIdx.x;
    const int stride = gridDim.x * blockDim.x;
    for (; i < n4; i += stride) {
        const float4 f = reinterpret_cast<const float4*>(src)[i];
        ushort4 o;
        uint u;
        u = __builtin_bit_cast(uint, f.x); o.x = (ushort)((u + 0x7FFFu + ((u >> 16) & 1u)) >> 16);
        u = __builtin_bit_cast(uint, f.y); o.y = (ushort)((u + 0x7FFFu + ((u >> 16) & 1u)) >> 16);
        u = __builtin_bit_cast(uint, f.z); o.z = (ushort)((u + 0x7FFFu + ((u >> 16) & 1u)) >> 16);
        u = __builtin_bit_cast(uint, f.w); o.w = (ushort)((u + 0x7FFFu + ((u >> 16) & 1u)) >> 16);
        reinterpret_cast<ushort4*>(dst)[i] = o;
    }
}

// ---------------- main fused kernel, bf16 table path ----------------
__global__ __launch_bounds__(256, 8) void nnue_bf16_kernel(
    const int* __restrict__ wf, const int* __restrict__ bf,
    const float* __restrict__ stm, const ushort* __restrict__ tb,
    const float* __restrict__ ft_bias,
    const float* __restrict__ W1, const float* __restrict__ b1,
    const float* __restrict__ W2, const float* __restrict__ b2,
    const float* __restrict__ Wo, const float* __restrict__ bo,
    float* __restrict__ out)
{
    __shared__ float4 accs[4][64];     // raw bag sums (no bias): [wave=(esub,side)][float4 slot]
    __shared__ float  xs[2 * 4 * 132]; // mixed+clipped x, bank-padded groups of 32 float4
    __shared__ float  y1s[2][32];

    const int t    = threadIdx.x;
    const int l    = t & 63;
    const int w    = t >> 6;   // wave 0..3
    const int side = w & 1;    // 0=white, 1=black
    const int esub = w >> 1;   // element of the pair this wave gathers
    const int half = l >> 5;   // which row of the pair-load this half-wave covers
    const int sub  = l & 31;   // 16B chunk within the 512B bf16 row

    const int* fptr = side ? bf : wf;

    // Phase-2 constants
    const int j = t >> 3;      // output neuron 0..31
    const int c = t & 7;       // chunk 0..7 (64 dims each)
    const float* w1p = W1 + j * 512 + c * 64;
    const float* x0p = &xs[(0 * 4 + (c >> 1)) * 132 + (c & 1) * 64];
    const float* x1p = &xs[(1 * 4 + (c >> 1)) * 132 + (c & 1) * 64];
    // Mix-phase constant
    const float4 fb4 = reinterpret_cast<const float4*>(ft_bias)[t & 63];

    for (int it = 0; it < NB / 2; ++it) {
        const int b0 = blockIdx.x * NB + it * 2;

        // ---- Phase 1: gather. One dwordx4 per wave covers TWO 512B bf16 rows. ----
        const int idxv = fptr[(size_t)(b0 + esub) * KFEAT + sub];
        float acc[8] = {0.f, 0.f, 0.f, 0.f, 0.f, 0.f, 0.f, 0.f};

        #pragma unroll
        for (int g = 0; g < 2; ++g) {
            uint4 v[8];
            #pragma unroll
            for (int p8 = 0; p8 < 8; ++p8) {
                const int p   = g * 8 + p8;
                const int row = __shfl(idxv, 2 * p + half, 64);
                v[p8] = *reinterpret_cast<const uint4*>(tb + row * 256 + sub * 8);
            }
            #pragma unroll
            for (int p8 = 0; p8 < 8; ++p8) {
                uint q;
                q = v[p8].x;
                acc[0] += __builtin_bit_cast(float, q << 16);
                acc[1] += __builtin_bit_cast(float, q & 0xFFFF0000u);
                q = v[p8].y;
                acc[2] += __builtin_bit_cast(float, q << 16);
                acc[3] += __builtin_bit_cast(float, q & 0xFFFF0000u);
                q = v[p8].z;
                acc[4] += __builtin_bit_cast(float, q << 16);
                acc[5] += __builtin_bit_cast(float, q & 0xFFFF0000u);
                q = v[p8].w;
                acc[6] += __builtin_bit_cast(float, q << 16);
                acc[7] += __builtin_bit_cast(float, q & 0xFFFF0000u);
            }
        }
        // combine the two half-wave row partials (same dims)
        #pragma unroll
        for (int i = 0; i < 8; ++i) acc[i] += __shfl_xor(acc[i], 32);
        if (half == 0) {
            accs[w][2 * sub]     = make_float4(acc[0], acc[1], acc[2], acc[3]);
            accs[w][2 * sub + 1] = make_float4(acc[4], acc[5], acc[6], acc[7]);
        }
        __syncthreads();

        // ---- Mixing + clip: x = crelu(s*wtm + (1-s)*btm + bias) ----
        {
            const int e  = t >> 7;         // element of the pair
            const int hf = (t >> 6) & 1;   // which 256-dim half of x
            const int i  = t & 63;
            const float s  = stm[b0 + e];
            const float os = 1.0f - s;
            const float4 wa = accs[e * 2 + 0][i];
            const float4 ba = accs[e * 2 + 1][i];
            float4 x;
            if (hf == 0) {
                x.x = clip01(fmaf(s, wa.x, fmaf(os, ba.x, fb4.x)));
                x.y = clip01(fmaf(s, wa.y, fmaf(os, ba.y, fb4.y)));
                x.z = clip01(fmaf(s, wa.z, fmaf(os, ba.z, fb4.z)));
                x.w = clip01(fmaf(s, wa.w, fmaf(os, ba.w, fb4.w)));
            } else {
                x.x = clip01(fmaf(s, ba.x, fmaf(os, wa.x, fb4.x)));
                x.y = clip01(fmaf(s, ba.y, fmaf(os, wa.y, fb4.y)));
                x.z = clip01(fmaf(s, ba.z, fmaf(os, wa.z, fb4.z)));
                x.w = clip01(fmaf(s, ba.w, fmaf(os, wa.w, fb4.w)));
            }
            const int slot = hf * 64 + i;
            const int g = slot >> 5, i4 = slot & 31;
            *reinterpret_cast<float4*>(&xs[(e * 4 + g) * 132 + i4 * 4]) = x;
        }
        __syncthreads();

        // ---- Phase 2: layer 1 (512 -> 32) for BOTH elements ----
        float a0 = 0.0f, a1 = 0.0f;
        #pragma unroll 16
        for (int ii = 0; ii < 64; ++ii) {
            const float wv = w1p[ii];
            a0 = fmaf(wv, x0p[ii], a0);
            a1 = fmaf(wv, x1p[ii], a1);
        }
        a0 += __shfl_xor(a0, 1); a0 += __shfl_xor(a0, 2); a0 += __shfl_xor(a0, 4);
        a1 += __shfl_xor(a1, 1); a1 += __shfl_xor(a1, 2); a1 += __shfl_xor(a1, 4);
        if (c == 0) {
            const float bj = b1[j];
            y1s[0][j] = clip01(a0 + bj);
            y1s[1][j] = clip01(a1 + bj);
        }
        __syncthreads();

        // ---- Phase 3: layer 2 (32 -> 32) + output head ----
        if (t < 64) {
            const int e = t >> 5, i = t & 31;
            float a2 = b2[i];
            #pragma unroll
            for (int k2 = 0; k2 < 32; ++k2)
                a2 = fmaf(y1s[e][k2], W2[i * 32 + k2], a2);
            a2 = clip01(a2);
            float p = a2 * Wo[i];
            p += __shfl_xor(p, 1);  p += __shfl_xor(p, 2);
            p += __shfl_xor(p, 4);  p += __shfl_xor(p, 8);
            p += __shfl_xor(p, 16);
            if (i == 0) out[b0 + e] = p + bo[0];
        }
        __syncthreads();
    }
}

// ---------------- fallback: fp32 table path (if ws too small) ----------------
__global__ __launch_bounds__(256, 6) void nnue_fused_kernel(
    const int* __restrict__ wf, const int* __restrict__ bf,
    const float* __restrict__ stm, const float* __restrict__ table,
    const float* __restrict__ ft_bias,
    const float* __restrict__ W1, const float* __restrict__ b1,
    const float* __restrict__ W2, const float* __restrict__ b2,
    const float* __restrict__ Wo, const float* __restrict__ bo,
    float* __restrict__ out)
{
    __shared__ float4 accs[4][64];
    __shared__ float  xs[2 * 4 * 132];
    __shared__ float  y1s[2][32];

    const int t    = threadIdx.x;
    const int l    = t & 63;
    const int w    = t >> 6;
    const int side = w & 1;
    const int esub = w >> 1;

    const float4 ftb4 = reinterpret_cast<const float4*>(ft_bias)[l];
    const int*   fptr = side ? bf : wf;

    const int j = t >> 3;
    const int c = t & 7;
    const float* w1p = W1 + j * 512 + c * 64;
    const float* x0p = &xs[(0 * 4 + (c >> 1)) * 132 + (c & 1) * 64];
    const float* x1p = &xs[(1 * 4 + (c >> 1)) * 132 + (c & 1) * 64];

    for (int it = 0; it < 8 / 2; ++it) {
        const int b0 = blockIdx.x * 8 + it * 2;

        int idxv = fptr[(size_t)(b0 + esub) * KFEAT + (l & 31)];
        float4 acc = ftb4;
        #pragma unroll
        for (int k = 0; k < KFEAT; ++k) {
            const int row = __builtin_amdgcn_readfirstlane(__shfl(idxv, k, 64));
            const float4 v = reinterpret_cast<const float4*>(table)[(size_t)row * 64 + l];
            acc.x += v.x; acc.y += v.y; acc.z += v.z; acc.w += v.w;
        }
        accs[w][l] = acc;
        __syncthreads();

        {
            const int e  = t >> 7;
            const int hf = (t >> 6) & 1;
            const int i  = t & 63;
            const float s  = stm[b0 + e];
            const float os = 1.0f - s;
            const float4 wa = accs[e * 2 + 0][i];
            const float4 ba = accs[e * 2 + 1][i];
            float4 x;
            if (hf == 0) {
                x.x = clip01(s * wa.x + os * ba.x);
                x.y = clip01(s * wa.y + os * ba.y);
                x.z = clip01(s * wa.z + os * ba.z);
                x.w = clip01(s * wa.w + os * ba.w);
            } else {
                x.x = clip01(s * ba.x + os * wa.x);
                x.y = clip01(s * ba.y + os * wa.y);
                x.z = clip01(s * ba.z + os * wa.z);
                x.w = clip01(s * ba.w + os * wa.w);
            }
            const int slot = hf * 64 + i;
            const int g = slot >> 5, i4 = slot & 31;
            *reinterpret_cast<float4*>(&xs[(e * 4 + g) * 132 + i4 * 4]) = x;
        }
        __syncthreads();

        float a0 = 0.0f, a1 = 0.0f;
        #pragma unroll 16
        for (int ii = 0; ii < 64; ++ii) {
            const float wv = w1p[ii];
            a0 = fmaf(wv, x0p[ii], a0);
            a1 = fmaf(wv, x1p[ii], a1);
        }
        a0 += __shfl_xor(a0, 1); a0 += __shfl_xor(a0, 2); a0 += __shfl_xor(a0, 4);
        a1 += __shfl_xor(a1, 1); a1 += __shfl_xor(a1, 2); a1 += __shfl_xor(a1, 4);
        if (c == 0) {
            const float bj = b1[j];
            y1s[0][j] = clip01(a0 + bj);
            y1s[1][j] = clip01(a1 + bj);
        }
        __syncthreads();

        if (t < 64) {
            const int e = t >> 5, i = t & 31;
            float a2 = b2[i];
            #pragma unroll
            for (int k2 = 0; k2 < 32; ++k2)
                a2 = fmaf(y1s[e][k2], W2[i * 32 + k2], a2);
            a2 = clip01(a2);
            float p = a2 * Wo[i];
            p += __shfl_xor(p, 1);  p += __shfl_xor(p, 2);
            p += __shfl_xor(p, 4);  p += __shfl_xor(p, 8);
            p += __shfl_xor(p, 16);
            if (i == 0) out[b0 + e] = p + bo[0];
        }
        __syncthreads();
    }
}

extern "C" void kernel_launch(void* const* d_in, const int* in_sizes, int n_in,
                              void* d_out, int out_size, void* d_ws, size_t ws_size,
                              hipStream_t stream) {
    const int*   wf      = (const int*)  d_in[0];
    const int*   bf      = (const int*)  d_in[2];
    const float* stm     = (const float*)d_in[4];
    const float* table   = (const float*)d_in[5];
    const float* ft_bias = (const float*)d_in[6];
    const float* W1      = (const float*)d_in[7];
    const float* b1      = (const float*)d_in[8];
    const float* W2      = (const float*)d_in[9];
    const float* b2      = (const float*)d_in[10];
    const float* Wo      = (const float*)d_in[11];
    const float* bo      = (const float*)d_in[12];
    float*       out     = (float*)d_out;

    const int B = in_sizes[1];                 // 16384
    const int tbl_elems = in_sizes[5];         // 40960*256
    const size_t need = (size_t)tbl_elems * sizeof(ushort);

    if (ws_size >= need) {
        ushort* tb = (ushort*)d_ws;
        convert_table_bf16<<<2048, 256, 0, stream>>>(table, tb, tbl_elems / 4);
        nnue_bf16_kernel<<<B / NB, 256, 0, stream>>>(
            wf, bf, stm, tb, ft_bias, W1, b1, W2, b2, Wo, bo, out);
    } else {
        nnue_fused_kernel<<<B / 8, 256, 0, stream>>>(
            wf, bf, stm, table, ft_bias, W1, b1, W2, b2, Wo, bo, out);
    }
}

// Round 4
// 150.926 us; speedup vs baseline: 1.5203x; 1.5203x over previous
//
#include <hip/hip_runtime.h>

#define KFEAT 32
#define NB 8   // batch elements per block (4 pair-iterations, one wave per bag-side)

__device__ __forceinline__ float clip01(float v) {
    return fminf(fmaxf(v, 0.0f), 1.0f);
}

// ---------------- fp32 table -> bf16 (RTNE) conversion, runs every launch ----------------
__global__ __launch_bounds__(256) void convert_table_bf16(
    const float* __restrict__ src, ushort* __restrict__ dst, int n4)
{
    int i = blockIdx.x * blockDim.x + threadIdx.x;
    const int stride = gridDim.x * blockDim.x;
    for (; i < n4; i += stride) {
        const float4 f = reinterpret_cast<const float4*>(src)[i];
        ushort4 o;
        uint u;
        u = __builtin_bit_cast(uint, f.x); o.x = (ushort)((u + 0x7FFFu + ((u >> 16) & 1u)) >> 16);
        u = __builtin_bit_cast(uint, f.y); o.y = (ushort)((u + 0x7FFFu + ((u >> 16) & 1u)) >> 16);
        u = __builtin_bit_cast(uint, f.z); o.z = (ushort)((u + 0x7FFFu + ((u >> 16) & 1u)) >> 16);
        u = __builtin_bit_cast(uint, f.w); o.w = (ushort)((u + 0x7FFFu + ((u >> 16) & 1u)) >> 16);
        reinterpret_cast<ushort4*>(dst)[i] = o;
    }
}

// ---------------- main fused kernel: bf16 table, SGPR-uniform row gather ----------------
__global__ __launch_bounds__(256, 8) void nnue_bf16_kernel(
    const int* __restrict__ wf, const int* __restrict__ bf,
    const float* __restrict__ stm, const ushort* __restrict__ tb,
    const float* __restrict__ ft_bias,
    const float* __restrict__ W1, const float* __restrict__ b1,
    const float* __restrict__ W2, const float* __restrict__ b2,
    const float* __restrict__ Wo, const float* __restrict__ bo,
    float* __restrict__ out)
{
    __shared__ float4 accs[4][64];     // raw bag sums (no bias): [wave=(esub,side)][float4 slot]
    __shared__ float  xs[2 * 4 * 132]; // mixed+clipped x, bank-padded groups of 32 float4
    __shared__ float  y1s[2][32];

    const int t    = threadIdx.x;
    const int l    = t & 63;
    const int w    = t >> 6;   // wave 0..3
    const int side = w & 1;    // 0=white, 1=black
    const int esub = w >> 1;   // element of the pair this wave gathers

    const int* fptr = side ? bf : wf;

    // Phase-2 constants
    const int j = t >> 3;      // output neuron 0..31
    const int c = t & 7;       // chunk 0..7 (64 dims each)
    const float* w1p = W1 + j * 512 + c * 64;
    const float* x0p = &xs[(0 * 4 + (c >> 1)) * 132 + (c & 1) * 64];
    const float* x1p = &xs[(1 * 4 + (c >> 1)) * 132 + (c & 1) * 64];
    // Mix-phase constant: bias for dims 4l..4l+3
    const float4 fb4 = reinterpret_cast<const float4*>(ft_bias)[l];

    for (int it = 0; it < NB / 2; ++it) {
        const int b0 = blockIdx.x * NB + it * 2;

        // ---- Phase 1: gather. Whole wave reads one 512B bf16 row per dwordx2. ----
        // Row index is wave-uniform (v_readlane -> SGPR base), lane covers dims 4l..4l+3.
        const int idxv = fptr[(size_t)(b0 + esub) * KFEAT + (l & 31)];
        float a0 = 0.f, a1 = 0.f, a2 = 0.f, a3 = 0.f;
        #pragma unroll
        for (int k = 0; k < KFEAT; ++k) {
            const int row = __builtin_amdgcn_readlane(idxv, k);
            const uint2 q = *reinterpret_cast<const uint2*>(tb + (size_t)row * 256 + l * 4);
            a0 += __builtin_bit_cast(float, q.x << 16);
            a1 += __builtin_bit_cast(float, q.x & 0xFFFF0000u);
            a2 += __builtin_bit_cast(float, q.y << 16);
            a3 += __builtin_bit_cast(float, q.y & 0xFFFF0000u);
        }
        accs[w][l] = make_float4(a0, a1, a2, a3);
        __syncthreads();

        // ---- Mixing + clip: x = crelu(s*wtm + (1-s)*btm + bias) ----
        {
            const int e  = t >> 7;         // element of the pair
            const int hf = (t >> 6) & 1;   // which 256-dim half of x
            const int i  = t & 63;
            const float s  = stm[b0 + e];
            const float os = 1.0f - s;
            const float4 wa = accs[e * 2 + 0][i];
            const float4 ba = accs[e * 2 + 1][i];
            const float4 fb = reinterpret_cast<const float4*>(ft_bias)[i];
            float4 x;
            if (hf == 0) {
                x.x = clip01(fmaf(s, wa.x, fmaf(os, ba.x, fb.x)));
                x.y = clip01(fmaf(s, wa.y, fmaf(os, ba.y, fb.y)));
                x.z = clip01(fmaf(s, wa.z, fmaf(os, ba.z, fb.z)));
                x.w = clip01(fmaf(s, wa.w, fmaf(os, ba.w, fb.w)));
            } else {
                x.x = clip01(fmaf(s, ba.x, fmaf(os, wa.x, fb.x)));
                x.y = clip01(fmaf(s, ba.y, fmaf(os, wa.y, fb.y)));
                x.z = clip01(fmaf(s, ba.z, fmaf(os, wa.z, fb.z)));
                x.w = clip01(fmaf(s, ba.w, fmaf(os, wa.w, fb.w)));
            }
            const int slot = hf * 64 + i;
            const int g = slot >> 5, i4 = slot & 31;
            *reinterpret_cast<float4*>(&xs[(e * 4 + g) * 132 + i4 * 4]) = x;
        }
        __syncthreads();

        // ---- Phase 2: layer 1 (512 -> 32) for BOTH elements ----
        float p0 = 0.0f, p1 = 0.0f;
        #pragma unroll 16
        for (int ii = 0; ii < 64; ++ii) {
            const float wv = w1p[ii];
            p0 = fmaf(wv, x0p[ii], p0);
            p1 = fmaf(wv, x1p[ii], p1);
        }
        p0 += __shfl_xor(p0, 1); p0 += __shfl_xor(p0, 2); p0 += __shfl_xor(p0, 4);
        p1 += __shfl_xor(p1, 1); p1 += __shfl_xor(p1, 2); p1 += __shfl_xor(p1, 4);
        if (c == 0) {
            const float bj = b1[j];
            y1s[0][j] = clip01(p0 + bj);
            y1s[1][j] = clip01(p1 + bj);
        }
        __syncthreads();

        // ---- Phase 3: layer 2 (32 -> 32) + output head ----
        if (t < 64) {
            const int e = t >> 5, i = t & 31;
            float acc2 = b2[i];
            #pragma unroll
            for (int k2 = 0; k2 < 32; ++k2)
                acc2 = fmaf(y1s[e][k2], W2[i * 32 + k2], acc2);
            acc2 = clip01(acc2);
            float p = acc2 * Wo[i];
            p += __shfl_xor(p, 1);  p += __shfl_xor(p, 2);
            p += __shfl_xor(p, 4);  p += __shfl_xor(p, 8);
            p += __shfl_xor(p, 16);
            if (i == 0) out[b0 + e] = p + bo[0];
        }
        __syncthreads();
        (void)fb4;
    }
}

// ---------------- fallback: fp32 table path (if ws too small) ----------------
__global__ __launch_bounds__(256, 6) void nnue_fused_kernel(
    const int* __restrict__ wf, const int* __restrict__ bf,
    const float* __restrict__ stm, const float* __restrict__ table,
    const float* __restrict__ ft_bias,
    const float* __restrict__ W1, const float* __restrict__ b1,
    const float* __restrict__ W2, const float* __restrict__ b2,
    const float* __restrict__ Wo, const float* __restrict__ bo,
    float* __restrict__ out)
{
    __shared__ float4 accs[4][64];
    __shared__ float  xs[2 * 4 * 132];
    __shared__ float  y1s[2][32];

    const int t    = threadIdx.x;
    const int l    = t & 63;
    const int w    = t >> 6;
    const int side = w & 1;
    const int esub = w >> 1;

    const float4 ftb4 = reinterpret_cast<const float4*>(ft_bias)[l];
    const int*   fptr = side ? bf : wf;

    const int j = t >> 3;
    const int c = t & 7;
    const float* w1p = W1 + j * 512 + c * 64;
    const float* x0p = &xs[(0 * 4 + (c >> 1)) * 132 + (c & 1) * 64];
    const float* x1p = &xs[(1 * 4 + (c >> 1)) * 132 + (c & 1) * 64];

    for (int it = 0; it < 8 / 2; ++it) {
        const int b0 = blockIdx.x * 8 + it * 2;

        int idxv = fptr[(size_t)(b0 + esub) * KFEAT + (l & 31)];
        float4 acc = ftb4;
        #pragma unroll
        for (int k = 0; k < KFEAT; ++k) {
            const int row = __builtin_amdgcn_readlane(idxv, k);
            const float4 v = reinterpret_cast<const float4*>(table)[(size_t)row * 64 + l];
            acc.x += v.x; acc.y += v.y; acc.z += v.z; acc.w += v.w;
        }
        accs[w][l] = acc;
        __syncthreads();

        {
            const int e  = t >> 7;
            const int hf = (t >> 6) & 1;
            const int i  = t & 63;
            const float s  = stm[b0 + e];
            const float os = 1.0f - s;
            const float4 wa = accs[e * 2 + 0][i];
            const float4 ba = accs[e * 2 + 1][i];
            float4 x;
            if (hf == 0) {
                x.x = clip01(s * wa.x + os * ba.x);
                x.y = clip01(s * wa.y + os * ba.y);
                x.z = clip01(s * wa.z + os * ba.z);
                x.w = clip01(s * wa.w + os * ba.w);
            } else {
                x.x = clip01(s * ba.x + os * wa.x);
                x.y = clip01(s * ba.y + os * wa.y);
                x.z = clip01(s * ba.z + os * wa.z);
                x.w = clip01(s * ba.w + os * wa.w);
            }
            const int slot = hf * 64 + i;
            const int g = slot >> 5, i4 = slot & 31;
            *reinterpret_cast<float4*>(&xs[(e * 4 + g) * 132 + i4 * 4]) = x;
        }
        __syncthreads();

        float a0 = 0.0f, a1 = 0.0f;
        #pragma unroll 16
        for (int ii = 0; ii < 64; ++ii) {
            const float wv = w1p[ii];
            a0 = fmaf(wv, x0p[ii], a0);
            a1 = fmaf(wv, x1p[ii], a1);
        }
        a0 += __shfl_xor(a0, 1); a0 += __shfl_xor(a0, 2); a0 += __shfl_xor(a0, 4);
        a1 += __shfl_xor(a1, 1); a1 += __shfl_xor(a1, 2); a1 += __shfl_xor(a1, 4);
        if (c == 0) {
            const float bj = b1[j];
            y1s[0][j] = clip01(a0 + bj);
            y1s[1][j] = clip01(a1 + bj);
        }
        __syncthreads();

        if (t < 64) {
            const int e = t >> 5, i = t & 31;
            float a2 = b2[i];
            #pragma unroll
            for (int k2 = 0; k2 < 32; ++k2)
                a2 = fmaf(y1s[e][k2], W2[i * 32 + k2], a2);
            a2 = clip01(a2);
            float p = a2 * Wo[i];
            p += __shfl_xor(p, 1);  p += __shfl_xor(p, 2);
            p += __shfl_xor(p, 4);  p += __shfl_xor(p, 8);
            p += __shfl_xor(p, 16);
            if (i == 0) out[b0 + e] = p + bo[0];
        }
        __syncthreads();
    }
}

extern "C" void kernel_launch(void* const* d_in, const int* in_sizes, int n_in,
                              void* d_out, int out_size, void* d_ws, size_t ws_size,
                              hipStream_t stream) {
    const int*   wf      = (const int*)  d_in[0];
    const int*   bf      = (const int*)  d_in[2];
    const float* stm     = (const float*)d_in[4];
    const float* table   = (const float*)d_in[5];
    const float* ft_bias = (const float*)d_in[6];
    const float* W1      = (const float*)d_in[7];
    const float* b1      = (const float*)d_in[8];
    const float* W2      = (const float*)d_in[9];
    const float* b2      = (const float*)d_in[10];
    const float* Wo      = (const float*)d_in[11];
    const float* bo      = (const float*)d_in[12];
    float*       out     = (float*)d_out;

    const int B = in_sizes[1];                 // 16384
    const int tbl_elems = in_sizes[5];         // 40960*256
    const size_t need = (size_t)tbl_elems * sizeof(ushort);

    if (ws_size >= need) {
        ushort* tb = (ushort*)d_ws;
        convert_table_bf16<<<2048, 256, 0, stream>>>(table, tb, tbl_elems / 4);
        nnue_bf16_kernel<<<B / NB, 256, 0, stream>>>(
            wf, bf, stm, tb, ft_bias, W1, b1, W2, b2, Wo, bo, out);
    } else {
        nnue_fused_kernel<<<B / 8, 256, 0, stream>>>(
            wf, bf, stm, table, ft_bias, W1, b1, W2, b2, Wo, bo, out);
    }
}

// Round 5
// 85.682 us; speedup vs baseline: 2.6779x; 1.7615x over previous
//
#include <hip/hip_runtime.h>

#define KFEAT 32
#define NB 8            // batch elements per block
#define XPITCH 544      // floats per element row in xs (8 chunks * 68)
#define APITCH 272      // floats per bag row in accs overlay (= XPITCH/2)

__device__ __forceinline__ float clip01(float v) {
    return fminf(fmaxf(v, 0.0f), 1.0f);
}
__device__ __forceinline__ float bfh(uint u) {   // high-16 as bf16 -> float
    return __builtin_bit_cast(float, u & 0xFFFF0000u);
}
__device__ __forceinline__ float bfl(uint u) {   // low-16 as bf16 -> float
    return __builtin_bit_cast(float, u << 16);
}

// ---------------- fp32 table -> bf16 (RTNE) conversion, runs every launch ----------------
__global__ __launch_bounds__(256) void convert_table_bf16(
    const float* __restrict__ src, ushort* __restrict__ dst, int n4)
{
    int i = blockIdx.x * blockDim.x + threadIdx.x;
    const int stride = gridDim.x * blockDim.x;
    for (; i < n4; i += stride) {
        const float4 f = reinterpret_cast<const float4*>(src)[i];
        ushort4 o;
        uint u;
        u = __builtin_bit_cast(uint, f.x); o.x = (ushort)((u + 0x7FFFu + ((u >> 16) & 1u)) >> 16);
        u = __builtin_bit_cast(uint, f.y); o.y = (ushort)((u + 0x7FFFu + ((u >> 16) & 1u)) >> 16);
        u = __builtin_bit_cast(uint, f.z); o.z = (ushort)((u + 0x7FFFu + ((u >> 16) & 1u)) >> 16);
        u = __builtin_bit_cast(uint, f.w); o.w = (ushort)((u + 0x7FFFu + ((u >> 16) & 1u)) >> 16);
        reinterpret_cast<ushort4*>(dst)[i] = o;
    }
}

// ---------------- main fused kernel: 8 elements/block, single gather phase ----------------
__global__ __launch_bounds__(256, 8) void nnue_bf16_kernel(
    const int* __restrict__ wf, const int* __restrict__ bf,
    const float* __restrict__ stm, const ushort* __restrict__ tb,
    const float* __restrict__ ft_bias,
    const float* __restrict__ W1, const float* __restrict__ b1,
    const float* __restrict__ W2, const float* __restrict__ b2,
    const float* __restrict__ Wo, const float* __restrict__ bo,
    float* __restrict__ out)
{
    // Union region: first accs[16][APITCH] (raw bag sums), then xs[8][XPITCH].
    __shared__ float lds[NB * XPITCH];
    __shared__ float y1s[NB][32];

    const int t   = threadIdx.x;
    const int l   = t & 63;
    const int w   = t >> 6;     // wave 0..3
    const int sub = l & 31;
    const int b0  = blockIdx.x * NB;

    // ---- Phase A: gather all 16 bags; 4 sequential bags per wave, no barriers ----
    // Row index is wave-uniform (v_readlane -> SGPR base); one dwordx2 per lane
    // covers the whole 512B bf16 row per load instruction.
    #pragma unroll
    for (int g = 0; g < 4; ++g) {
        const int bag  = g * 4 + w;        // 0..15
        const int e    = bag >> 1;
        const int side = bag & 1;
        const int* fp  = side ? bf : wf;
        const int idxv = fp[(size_t)(b0 + e) * KFEAT + sub];
        float a0 = 0.f, a1 = 0.f, a2 = 0.f, a3 = 0.f;
        #pragma unroll
        for (int k = 0; k < KFEAT; ++k) {
            const int row = __builtin_amdgcn_readlane(idxv, k);
            const uint2 q = *reinterpret_cast<const uint2*>(tb + (size_t)row * 256 + l * 4);
            a0 += bfl(q.x); a1 += bfh(q.x);
            a2 += bfl(q.y); a3 += bfh(q.y);
        }
        *reinterpret_cast<float4*>(&lds[bag * APITCH + l * 4]) =
            make_float4(a0, a1, a2, a3);
    }
    __syncthreads();

    // ---- Phase B: mix + clip, in-place overlay (read all -> barrier -> write) ----
    {
        const int e = t >> 5, r = t & 31;
        const float s  = stm[b0 + e];
        const float os = 1.0f - s;
        const float4 wa0 = *reinterpret_cast<const float4*>(&lds[(2 * e + 0) * APITCH + 4 * r]);
        const float4 ba0 = *reinterpret_cast<const float4*>(&lds[(2 * e + 1) * APITCH + 4 * r]);
        const float4 wa1 = *reinterpret_cast<const float4*>(&lds[(2 * e + 0) * APITCH + 4 * (r + 32)]);
        const float4 ba1 = *reinterpret_cast<const float4*>(&lds[(2 * e + 1) * APITCH + 4 * (r + 32)]);
        const float4 fb0 = reinterpret_cast<const float4*>(ft_bias)[r];
        const float4 fb1 = reinterpret_cast<const float4*>(ft_bias)[r + 32];
        __syncthreads();

        // d = hf*256 + 4*i  ->  xs addr: e*XPITCH + (d>>6)*68 + (d&63)
        #define MIXW(wa, ba, fb, i, hf)                                              \
        {                                                                            \
            float4 xv;                                                               \
            if (hf == 0) {                                                           \
                xv.x = clip01(fmaf(s, (wa).x, fmaf(os, (ba).x, (fb).x)));            \
                xv.y = clip01(fmaf(s, (wa).y, fmaf(os, (ba).y, (fb).y)));            \
                xv.z = clip01(fmaf(s, (wa).z, fmaf(os, (ba).z, (fb).z)));            \
                xv.w = clip01(fmaf(s, (wa).w, fmaf(os, (ba).w, (fb).w)));            \
            } else {                                                                 \
                xv.x = clip01(fmaf(s, (ba).x, fmaf(os, (wa).x, (fb).x)));            \
                xv.y = clip01(fmaf(s, (ba).y, fmaf(os, (wa).y, (fb).y)));            \
                xv.z = clip01(fmaf(s, (ba).z, fmaf(os, (wa).z, (fb).z)));            \
                xv.w = clip01(fmaf(s, (ba).w, fmaf(os, (wa).w, (fb).w)));            \
            }                                                                        \
            const int d = (hf) * 256 + 4 * (i);                                      \
            *reinterpret_cast<float4*>(&lds[e * XPITCH + (d >> 6) * 68 + (d & 63)]) = xv; \
        }
        MIXW(wa0, ba0, fb0, r,      0)
        MIXW(wa1, ba1, fb1, r + 32, 0)
        MIXW(wa0, ba0, fb0, r,      1)
        MIXW(wa1, ba1, fb1, r + 32, 1)
        #undef MIXW
    }
    __syncthreads();

    // ---- Phase C: layer 1 (512 -> 32) for all 8 elements; W1 read once per block ----
    {
        const int j = t >> 3;   // output neuron 0..31
        const int c = t & 7;    // 64-dim chunk 0..7
        const float* w1p = W1 + j * 512 + c * 64;
        float acc[NB] = {0.f, 0.f, 0.f, 0.f, 0.f, 0.f, 0.f, 0.f};
        #pragma unroll
        for (int blk = 0; blk < 4; ++blk) {
            const float4 wv0 = reinterpret_cast<const float4*>(w1p + blk * 16)[0];
            const float4 wv1 = reinterpret_cast<const float4*>(w1p + blk * 16)[1];
            const float4 wv2 = reinterpret_cast<const float4*>(w1p + blk * 16)[2];
            const float4 wv3 = reinterpret_cast<const float4*>(w1p + blk * 16)[3];
            #pragma unroll
            for (int e = 0; e < NB; ++e) {
                const float* xp = &lds[e * XPITCH + c * 68 + blk * 16];
                const float4 x0 = *reinterpret_cast<const float4*>(xp + 0);
                const float4 x1 = *reinterpret_cast<const float4*>(xp + 4);
                const float4 x2 = *reinterpret_cast<const float4*>(xp + 8);
                const float4 x3 = *reinterpret_cast<const float4*>(xp + 12);
                float a = acc[e];
                a = fmaf(wv0.x, x0.x, a); a = fmaf(wv0.y, x0.y, a);
                a = fmaf(wv0.z, x0.z, a); a = fmaf(wv0.w, x0.w, a);
                a = fmaf(wv1.x, x1.x, a); a = fmaf(wv1.y, x1.y, a);
                a = fmaf(wv1.z, x1.z, a); a = fmaf(wv1.w, x1.w, a);
                a = fmaf(wv2.x, x2.x, a); a = fmaf(wv2.y, x2.y, a);
                a = fmaf(wv2.z, x2.z, a); a = fmaf(wv2.w, x2.w, a);
                a = fmaf(wv3.x, x3.x, a); a = fmaf(wv3.y, x3.y, a);
                a = fmaf(wv3.z, x3.z, a); a = fmaf(wv3.w, x3.w, a);
                acc[e] = a;
            }
        }
        #pragma unroll
        for (int e = 0; e < NB; ++e) {
            acc[e] += __shfl_xor(acc[e], 1);
            acc[e] += __shfl_xor(acc[e], 2);
            acc[e] += __shfl_xor(acc[e], 4);
        }
        if (c == 0) {
            const float bj = b1[j];
            #pragma unroll
            for (int e = 0; e < NB; ++e)
                y1s[e][j] = clip01(acc[e] + bj);
        }
    }
    __syncthreads();

    // ---- Phase D: layer 2 (32 -> 32) + output head; thread = (element, neuron) ----
    {
        const int e = t >> 5, i = t & 31;
        const float4* w2p = reinterpret_cast<const float4*>(W2 + i * 32);
        float a2 = b2[i];
        #pragma unroll
        for (int kq = 0; kq < 8; ++kq) {
            const float4 wq = w2p[kq];
            const float4 yq = *reinterpret_cast<const float4*>(&y1s[e][kq * 4]);
            a2 = fmaf(wq.x, yq.x, a2); a2 = fmaf(wq.y, yq.y, a2);
            a2 = fmaf(wq.z, yq.z, a2); a2 = fmaf(wq.w, yq.w, a2);
        }
        a2 = clip01(a2);
        float p = a2 * Wo[i];
        p += __shfl_xor(p, 1);  p += __shfl_xor(p, 2);
        p += __shfl_xor(p, 4);  p += __shfl_xor(p, 8);
        p += __shfl_xor(p, 16);
        if (i == 0) out[b0 + e] = p + bo[0];
    }
}

// ---------------- fallback: fp32 table path (if ws too small) ----------------
__global__ __launch_bounds__(256, 6) void nnue_fused_kernel(
    const int* __restrict__ wf, const int* __restrict__ bf,
    const float* __restrict__ stm, const float* __restrict__ table,
    const float* __restrict__ ft_bias,
    const float* __restrict__ W1, const float* __restrict__ b1,
    const float* __restrict__ W2, const float* __restrict__ b2,
    const float* __restrict__ Wo, const float* __restrict__ bo,
    float* __restrict__ out)
{
    __shared__ float4 accs[4][64];
    __shared__ float  xs[2 * 4 * 132];
    __shared__ float  y1s[2][32];

    const int t    = threadIdx.x;
    const int l    = t & 63;
    const int w    = t >> 6;
    const int side = w & 1;
    const int esub = w >> 1;

    const float4 ftb4 = reinterpret_cast<const float4*>(ft_bias)[l];
    const int*   fptr = side ? bf : wf;

    const int j = t >> 3;
    const int c = t & 7;
    const float* w1p = W1 + j * 512 + c * 64;
    const float* x0p = &xs[(0 * 4 + (c >> 1)) * 132 + (c & 1) * 64];
    const float* x1p = &xs[(1 * 4 + (c >> 1)) * 132 + (c & 1) * 64];

    for (int it = 0; it < 8 / 2; ++it) {
        const int b0 = blockIdx.x * 8 + it * 2;

        int idxv = fptr[(size_t)(b0 + esub) * KFEAT + (l & 31)];
        float4 acc = ftb4;
        #pragma unroll
        for (int k = 0; k < KFEAT; ++k) {
            const int row = __builtin_amdgcn_readlane(idxv, k);
            const float4 v = reinterpret_cast<const float4*>(table)[(size_t)row * 64 + l];
            acc.x += v.x; acc.y += v.y; acc.z += v.z; acc.w += v.w;
        }
        accs[w][l] = acc;
        __syncthreads();

        {
            const int e  = t >> 7;
            const int hf = (t >> 6) & 1;
            const int i  = t & 63;
            const float s  = stm[b0 + e];
            const float os = 1.0f - s;
            const float4 wa = accs[e * 2 + 0][i];
            const float4 ba = accs[e * 2 + 1][i];
            float4 x;
            if (hf == 0) {
                x.x = clip01(s * wa.x + os * ba.x);
                x.y = clip01(s * wa.y + os * ba.y);
                x.z = clip01(s * wa.z + os * ba.z);
                x.w = clip01(s * wa.w + os * ba.w);
            } else {
                x.x = clip01(s * ba.x + os * wa.x);
                x.y = clip01(s * ba.y + os * wa.y);
                x.z = clip01(s * ba.z + os * wa.z);
                x.w = clip01(s * ba.w + os * wa.w);
            }
            const int slot = hf * 64 + i;
            const int g = slot >> 5, i4 = slot & 31;
            *reinterpret_cast<float4*>(&xs[(e * 4 + g) * 132 + i4 * 4]) = x;
        }
        __syncthreads();

        float a0 = 0.0f, a1 = 0.0f;
        #pragma unroll 16
        for (int ii = 0; ii < 64; ++ii) {
            const float wv = w1p[ii];
            a0 = fmaf(wv, x0p[ii], a0);
            a1 = fmaf(wv, x1p[ii], a1);
        }
        a0 += __shfl_xor(a0, 1); a0 += __shfl_xor(a0, 2); a0 += __shfl_xor(a0, 4);
        a1 += __shfl_xor(a1, 1); a1 += __shfl_xor(a1, 2); a1 += __shfl_xor(a1, 4);
        if (c == 0) {
            const float bj = b1[j];
            y1s[0][j] = clip01(a0 + bj);
            y1s[1][j] = clip01(a1 + bj);
        }
        __syncthreads();

        if (t < 64) {
            const int e = t >> 5, i = t & 31;
            float a2 = b2[i];
            #pragma unroll
            for (int k2 = 0; k2 < 32; ++k2)
                a2 = fmaf(y1s[e][k2], W2[i * 32 + k2], a2);
            a2 = clip01(a2);
            float p = a2 * Wo[i];
            p += __shfl_xor(p, 1);  p += __shfl_xor(p, 2);
            p += __shfl_xor(p, 4);  p += __shfl_xor(p, 8);
            p += __shfl_xor(p, 16);
            if (i == 0) out[b0 + e] = p + bo[0];
        }
        __syncthreads();
    }
}

extern "C" void kernel_launch(void* const* d_in, const int* in_sizes, int n_in,
                              void* d_out, int out_size, void* d_ws, size_t ws_size,
                              hipStream_t stream) {
    const int*   wf      = (const int*)  d_in[0];
    const int*   bf      = (const int*)  d_in[2];
    const float* stm     = (const float*)d_in[4];
    const float* table   = (const float*)d_in[5];
    const float* ft_bias = (const float*)d_in[6];
    const float* W1      = (const float*)d_in[7];
    const float* b1      = (const float*)d_in[8];
    const float* W2      = (const float*)d_in[9];
    const float* b2      = (const float*)d_in[10];
    const float* Wo      = (const float*)d_in[11];
    const float* bo      = (const float*)d_in[12];
    float*       out     = (float*)d_out;

    const int B = in_sizes[1];                 // 16384
    const int tbl_elems = in_sizes[5];         // 40960*256
    const size_t need = (size_t)tbl_elems * sizeof(ushort);

    if (ws_size >= need) {
        ushort* tb = (ushort*)d_ws;
        convert_table_bf16<<<2048, 256, 0, stream>>>(table, tb, tbl_elems / 4);
        nnue_bf16_kernel<<<B / NB, 256, 0, stream>>>(
            wf, bf, stm, tb, ft_bias, W1, b1, W2, b2, Wo, bo, out);
    } else {
        nnue_fused_kernel<<<B / 8, 256, 0, stream>>>(
            wf, bf, stm, table, ft_bias, W1, b1, W2, b2, Wo, bo, out);
    }
}